// Round 2
// baseline (2797.708 us; speedup 1.0000x reference)
//
#include <hip/hip_runtime.h>

// Problem constants
#define SEQ 512
#define HID 400
#define GATES 1600   // 4*HID
#define E1 800       // 2*HID
#define NWG 10       // workgroups per direction in the recurrence

__device__ __forceinline__ float bf2f(unsigned short u) {
    return __uint_as_float(((unsigned)u) << 16);
}
__device__ __forceinline__ unsigned short f2bf(float f) {
    unsigned u = __float_as_uint(f);
    u += 0x7FFFu + ((u >> 16) & 1u);   // RNE
    return (unsigned short)(u >> 16);
}
__device__ __forceinline__ float sigm(float x) { return 1.f / (1.f + __expf(-x)); }
__device__ __forceinline__ float tanh_f(float x) {
    float xc = fminf(fmaxf(x, -15.f), 15.f);
    float e = __expf(2.f * xc);
    return (e - 1.f) / (e + 1.f);
}
// load element i of an external float tensor that is either f32 or bf16
__device__ __forceinline__ float loadx(const void* p, size_t i, int isbf) {
    return isbf ? bf2f(((const unsigned short*)p)[i]) : ((const float*)p)[i];
}

// ------------------------------------------------------------ dtype detector
// bf16 data: ~100% of u16 halves have exponent-field in [100,130].
// f32 data (scale ~0.05): high halves pass, low halves (mantissa bits) ~12%.
__global__ void detect_kernel(const unsigned short* __restrict__ wemb,
                              unsigned* __restrict__ dtf) {
    __shared__ int cnt;
    if (threadIdx.x == 0) cnt = 0;
    __syncthreads();
    int pass = 0;
    for (int i = 0; i < 8; ++i) {
        unsigned short u = wemb[threadIdx.x * 8 + i];
        int e = (u >> 7) & 0xFF;
        pass += (e >= 100 && e <= 130) ? 1 : 0;
    }
    atomicAdd(&cnt, pass);
    __syncthreads();
    if (threadIdx.x == 0) *dtf = (cnt >= 1843) ? 1u : 0u;   // 90% of 2048
}

// ---------------------------------------------------------------- embedding
__global__ void embed_kernel(const int* __restrict__ words, const int* __restrict__ tags,
                             const void* __restrict__ wemb, const void* __restrict__ temb,
                             float* __restrict__ x /* [SEQ][400] f32 */,
                             const unsigned* __restrict__ dtf) {
    int t = blockIdx.x;
    int w = words[t], g = tags[t];
    int isbf = (int)*dtf;
    for (int k = threadIdx.x; k < HID; k += blockDim.x) {
        float v = (k < 300) ? loadx(wemb, (size_t)w * 300 + k, isbf)
                            : loadx(temb, (size_t)g * 100 + (k - 300), isbf);
        x[(size_t)t * HID + k] = v;
    }
}

// ---------------------------------------------------------- input projection
// xi[d][t][n] = sum_k A[t][k] * W[d*1600+n][k] + b_ih[d][n] + b_hh[d][n]
// Classic 64x64-tile f32 GEMM (A is always our internal f32 buffer; W/bias
// are external and branch on the dtype flag).
__global__ __launch_bounds__(256) void proj_kernel(
        const float* __restrict__ A /* [SEQ][K] */,
        const void* __restrict__ Wraw /* [2][GATES][K] */,
        const void* __restrict__ bihRaw, const void* __restrict__ bhhRaw,
        float* __restrict__ xi /* [2][SEQ][GATES] */,
        int K, const unsigned* __restrict__ dtf) {
    const int isbf = (int)*dtf;
    __shared__ float As[16][68];
    __shared__ float Ws[16][68];
    int tid = threadIdx.x;
    int t0 = blockIdx.x * 64, n0 = blockIdx.y * 64, dir = blockIdx.z;
    int lr = tid >> 2;              // loader row 0..63
    int lc = (tid & 3) * 4;         // loader k-offset {0,4,8,12}
    int tx = (tid & 15) * 4;        // this thread's n-offset
    int ty = (tid >> 4) * 4;        // this thread's t-offset

    const float* Af = A + (size_t)(t0 + lr) * K + lc;
    size_t wrow = (size_t)(dir * GATES + n0 + lr) * K + lc;
    const float* Wf = (const float*)Wraw + wrow;
    const unsigned short* Wh = (const unsigned short*)Wraw + wrow;

    float acc[4][4] = {};
    for (int k0 = 0; k0 < K; k0 += 16) {
        float4 av = *(const float4*)(Af + k0);
        float4 wv;
        if (isbf) {
            ushort4 w4 = *(const ushort4*)(Wh + k0);
            wv = make_float4(bf2f(w4.x), bf2f(w4.y), bf2f(w4.z), bf2f(w4.w));
        } else {
            wv = *(const float4*)(Wf + k0);
        }
        __syncthreads();
        As[lc + 0][lr] = av.x; As[lc + 1][lr] = av.y;
        As[lc + 2][lr] = av.z; As[lc + 3][lr] = av.w;
        Ws[lc + 0][lr] = wv.x; Ws[lc + 1][lr] = wv.y;
        Ws[lc + 2][lr] = wv.z; Ws[lc + 3][lr] = wv.w;
        __syncthreads();
#pragma unroll
        for (int kk = 0; kk < 16; ++kk) {
            float4 a = *(const float4*)&As[kk][ty];
            float4 w = *(const float4*)&Ws[kk][tx];
            float av4[4] = {a.x, a.y, a.z, a.w};
            float wv4[4] = {w.x, w.y, w.z, w.w};
#pragma unroll
            for (int i = 0; i < 4; ++i)
#pragma unroll
                for (int j = 0; j < 4; ++j)
                    acc[i][j] = fmaf(av4[i], wv4[j], acc[i][j]);
        }
    }
    float bias[4];
#pragma unroll
    for (int j = 0; j < 4; ++j) {
        int n = n0 + tx + j;
        bias[j] = loadx(bihRaw, dir * GATES + n, isbf) + loadx(bhhRaw, dir * GATES + n, isbf);
    }
    float* xout = xi + (size_t)dir * SEQ * GATES;
#pragma unroll
    for (int i = 0; i < 4; ++i) {
        int t = t0 + ty + i;
#pragma unroll
        for (int j = 0; j < 4; ++j)
            xout[(size_t)t * GATES + n0 + tx + j] = acc[i][j] + bias[j];
    }
}

// ------------------------------------------------------------- LSTM recurrence
// One layer, both directions. 20 WGs x 640 threads; WG owns 40 h-outputs
// (160 gate rows). Weights register-resident f32: lane(rg=tid/20, chunk=tid%20)
// holds rows lr=5*rg..5*rg+4, cols 20*chunk..+19. Cross-WG h exchange through
// device-scope atomics + monotonic per-WG flags.
__global__ __launch_bounds__(640) void rec_kernel(
        const float* __restrict__ xi /* [2][SEQ][GATES] */,
        const void* __restrict__ whhRaw /* [2][GATES][HID] */,
        float* __restrict__ hout /* [SEQ][E1]: 0..399 fwd, 400..799 bwd */,
        unsigned* __restrict__ flags /* [2*NWG], pre-zeroed */,
        const unsigned* __restrict__ dtf) {
    int tid = threadIdx.x;
    int bid = blockIdx.x;          // 0..19
    int dir = bid / NWG;
    int wg  = bid % NWG;
    int chunk = tid % 20;
    int rg    = tid / 20;          // 0..31
    const int isbf = (int)*dtf;

    __shared__ __align__(16) float hbuf[HID];
    __shared__ __align__(16) float partials[160][20];
    __shared__ __align__(16) float gates[160];

    // ---- load this lane's weight tile (f32, stays in VGPRs)
    float wv[5][20];
#pragma unroll
    for (int r = 0; r < 5; ++r) {
        int lr = rg * 5 + r;                // local row 0..159
        int jj = lr >> 2, gg = lr & 3;      // h index, gate (i,f,g,o)
        int grow = gg * HID + wg * 40 + jj; // global gate row
        size_t base = ((size_t)dir * GATES + grow) * HID + chunk * 20;
        if (isbf) {
            const ushort4* s4 = (const ushort4*)((const unsigned short*)whhRaw + base);
#pragma unroll
            for (int c4 = 0; c4 < 5; ++c4) {
                ushort4 w4 = s4[c4];
                wv[r][c4 * 4 + 0] = bf2f(w4.x); wv[r][c4 * 4 + 1] = bf2f(w4.y);
                wv[r][c4 * 4 + 2] = bf2f(w4.z); wv[r][c4 * 4 + 3] = bf2f(w4.w);
            }
        } else {
            const float4* s4 = (const float4*)((const float*)whhRaw + base);
#pragma unroll
            for (int c4 = 0; c4 < 5; ++c4) {
                float4 w4 = s4[c4];
                wv[r][c4 * 4 + 0] = w4.x; wv[r][c4 * 4 + 1] = w4.y;
                wv[r][c4 * 4 + 2] = w4.z; wv[r][c4 * 4 + 3] = w4.w;
            }
        }
    }

    int xrow = 0;
    if (tid < 160) { int jj = tid >> 2, gg = tid & 3; xrow = gg * HID + wg * 40 + jj; }
    const float* xibase = xi + (size_t)dir * SEQ * GATES;
    float cstate = 0.f;                    // lane tid<40 owns c for h-idx wg*40+tid
    int fbase = dir * NWG;

#pragma unroll 1
    for (int k = 0; k < SEQ; ++k) {
        int t = dir ? (SEQ - 1 - k) : k;
        float xiv = 0.f;
        if (tid < 160) xiv = xibase[(size_t)t * GATES + xrow];

        if (k > 0) {
            int tprev = dir ? (t + 1) : (t - 1);
            if (tid < NWG) {
                while (__hip_atomic_load(&flags[fbase + tid], __ATOMIC_RELAXED,
                                         __HIP_MEMORY_SCOPE_AGENT) < (unsigned)k)
                    __builtin_amdgcn_s_sleep(1);
            }
            __syncthreads();
            if (tid < HID)
                hbuf[tid] = __hip_atomic_load(&hout[(size_t)tprev * E1 + dir * HID + tid],
                                              __ATOMIC_RELAXED, __HIP_MEMORY_SCOPE_AGENT);
        } else {
            if (tid < HID) hbuf[tid] = 0.f;
        }
        __syncthreads();

        // ---- dot: 5 rows x 20 cols per lane, h broadcast from LDS
        float acc[5] = {0.f, 0.f, 0.f, 0.f, 0.f};
#pragma unroll
        for (int c4 = 0; c4 < 5; ++c4) {
            float4 hv = *(const float4*)&hbuf[chunk * 20 + c4 * 4];
#pragma unroll
            for (int r = 0; r < 5; ++r) {
                acc[r] += wv[r][c4 * 4 + 0] * hv.x + wv[r][c4 * 4 + 1] * hv.y +
                          wv[r][c4 * 4 + 2] * hv.z + wv[r][c4 * 4 + 3] * hv.w;
            }
        }
#pragma unroll
        for (int r = 0; r < 5; ++r) partials[rg * 5 + r][chunk] = acc[r];
        __syncthreads();

        // ---- reduce 20 column-chunks per gate row, add xi
        if (tid < 160) {
            const float4* pr = (const float4*)&partials[tid][0];
            float4 p0 = pr[0], p1 = pr[1], p2 = pr[2], p3 = pr[3], p4 = pr[4];
            float s = p0.x + p0.y + p0.z + p0.w
                    + p1.x + p1.y + p1.z + p1.w
                    + p2.x + p2.y + p2.z + p2.w
                    + p3.x + p3.y + p3.z + p3.w
                    + p4.x + p4.y + p4.z + p4.w;
            gates[tid] = s + xiv;
        }
        __syncthreads();

        // ---- nonlinearity + state update + publish h (device-scope)
        if (tid < 40) {
            float4 g4 = *(const float4*)&gates[tid * 4];   // (i,f,g,o)
            float ig = sigm(g4.x), fg = sigm(g4.y), cg = tanh_f(g4.z), og = sigm(g4.w);
            cstate = fg * cstate + ig * cg;
            float hv = og * tanh_f(cstate);
            __hip_atomic_store(&hout[(size_t)t * E1 + dir * HID + wg * 40 + tid], hv,
                               __ATOMIC_RELAXED, __HIP_MEMORY_SCOPE_AGENT);
        }
        __syncthreads();   // drains vmcnt: h stores visible before flag release
        if (tid == 0)
            __hip_atomic_store(&flags[fbase + wg], (unsigned)(k + 1),
                               __ATOMIC_RELEASE, __HIP_MEMORY_SCOPE_AGENT);
    }
}

// --------------------------------------------- head/dep projections (s, t)
__global__ void st_kernel(const float* __restrict__ h1 /* [SEQ][E1] */,
                          const void* __restrict__ fw /* [1600] */,
                          float* __restrict__ sv, float* __restrict__ tv,
                          const unsigned* __restrict__ dtf) {
    int i = blockIdx.x;
    int lane = threadIdx.x;
    int isbf = (int)*dtf;
    float s = 0.f, t = 0.f;
    for (int j = lane; j < E1; j += 64) {
        float hv = h1[(size_t)i * E1 + j];
        s += hv * loadx(fw, j, isbf);
        t += hv * loadx(fw, E1 + j, isbf);
    }
#pragma unroll
    for (int o = 32; o > 0; o >>= 1) {
        s += __shfl_xor(s, o, 64);
        t += __shfl_xor(t, o, 64);
    }
    if (lane == 0) { sv[i] = s; tv[i] = t; }
}

// ------------------------------------------------------------- final scores
__global__ void scores_kernel(const float* __restrict__ sv, const float* __restrict__ tv,
                              const void* __restrict__ fb, void* __restrict__ out,
                              const unsigned* __restrict__ dtf) {
    int idx = blockIdx.x * blockDim.x + threadIdx.x;   // < SEQ*SEQ
    int i = idx >> 9, j = idx & 511;
    int isbf = (int)*dtf;
    float v = tanh_f(sv[i] + tv[j] + loadx(fb, 0, isbf));
    if (isbf) ((unsigned short*)out)[idx] = f2bf(v);
    else      ((float*)out)[idx] = v;
}

// ---------------------------------------------------------------- workspace
static constexpr size_t OFF_X   = 0;           // 512*400*4   =   819,200
static constexpr size_t OFF_XI  = 819200;      // 2*512*1600*4 = 6,553,600
static constexpr size_t OFF_H0  = 7372800;     // 512*800*4   = 1,638,400
static constexpr size_t OFF_H1  = 9011200;     // 1,638,400
static constexpr size_t OFF_SV  = 10649600;    // 2048
static constexpr size_t OFF_TV  = 10651648;    // 2048
static constexpr size_t OFF_FLG = 10653696;    // 256 (40 sync flags used)
static constexpr size_t OFF_DTF = 10653952;    // 4

extern "C" void kernel_launch(void* const* d_in, const int* in_sizes, int n_in,
                              void* d_out, int out_size, void* d_ws, size_t ws_size,
                              hipStream_t stream) {
    const int* words = (const int*)d_in[0];
    const int* tags  = (const int*)d_in[1];
    const void* wemb = d_in[3];
    const void* temb = d_in[4];
    const void* wih0 = d_in[5];
    const void* whh0 = d_in[6];
    const void* bih0 = d_in[7];
    const void* bhh0 = d_in[8];
    const void* wih1 = d_in[9];
    const void* whh1 = d_in[10];
    const void* bih1 = d_in[11];
    const void* bhh1 = d_in[12];
    const void* fw   = d_in[13];
    const void* fb   = d_in[14];

    char* ws = (char*)d_ws;
    float* x        = (float*)(ws + OFF_X);
    float* xi       = (float*)(ws + OFF_XI);
    float* h0       = (float*)(ws + OFF_H0);
    float* h1       = (float*)(ws + OFF_H1);
    float* sv       = (float*)(ws + OFF_SV);
    float* tv       = (float*)(ws + OFF_TV);
    unsigned* flags = (unsigned*)(ws + OFF_FLG);
    unsigned* dtf   = (unsigned*)(ws + OFF_DTF);

    // sync flags must start at 0 every launch (ws is re-poisoned to 0xAA)
    hipMemsetAsync(flags, 0, 256, stream);
    detect_kernel<<<1, 256, 0, stream>>>((const unsigned short*)wemb, dtf);

    embed_kernel<<<SEQ, 128, 0, stream>>>(words, tags, wemb, temb, x, dtf);

    // layer 0
    proj_kernel<<<dim3(8, 25, 2), 256, 0, stream>>>(x, wih0, bih0, bhh0, xi, HID, dtf);
    rec_kernel<<<2 * NWG, 640, 0, stream>>>(xi, whh0, h0, flags, dtf);

    // layer 1 (reuses xi buffer)
    proj_kernel<<<dim3(8, 25, 2), 256, 0, stream>>>(h0, wih1, bih1, bhh1, xi, E1, dtf);
    rec_kernel<<<2 * NWG, 640, 0, stream>>>(xi, whh1, h1, flags + 20, dtf);

    // pairwise scores
    st_kernel<<<SEQ, 64, 0, stream>>>(h1, fw, sv, tv, dtf);
    scores_kernel<<<(SEQ * SEQ) / 256, 256, 0, stream>>>(sv, tv, fb, d_out, dtf);
}

// Round 3
// 2238.944 us; speedup vs baseline: 1.2496x; 1.2496x over previous
//
#include <hip/hip_runtime.h>

// Problem constants
#define SEQ 512
#define HID 400
#define GATES 1600   // 4*HID
#define E1 800       // 2*HID
#define NWG 10       // workgroups per direction in the recurrence

__device__ __forceinline__ float bf2f(unsigned short u) {
    return __uint_as_float(((unsigned)u) << 16);
}
__device__ __forceinline__ unsigned short f2bf(float f) {
    unsigned u = __float_as_uint(f);
    u += 0x7FFFu + ((u >> 16) & 1u);   // RNE
    return (unsigned short)(u >> 16);
}
__device__ __forceinline__ float sigm(float x) { return 1.f / (1.f + __expf(-x)); }
__device__ __forceinline__ float tanh_f(float x) {
    float xc = fminf(fmaxf(x, -15.f), 15.f);
    float e = __expf(2.f * xc);
    return (e - 1.f) / (e + 1.f);
}
// load element i of an external float tensor that is either f32 or bf16
__device__ __forceinline__ float loadx(const void* p, size_t i, int isbf) {
    return isbf ? bf2f(((const unsigned short*)p)[i]) : ((const float*)p)[i];
}

// ------------------------------------------------------------ dtype detector
__global__ void detect_kernel(const unsigned short* __restrict__ wemb,
                              unsigned* __restrict__ dtf) {
    __shared__ int cnt;
    if (threadIdx.x == 0) cnt = 0;
    __syncthreads();
    int pass = 0;
    for (int i = 0; i < 8; ++i) {
        unsigned short u = wemb[threadIdx.x * 8 + i];
        int e = (u >> 7) & 0xFF;
        pass += (e >= 100 && e <= 130) ? 1 : 0;
    }
    atomicAdd(&cnt, pass);
    __syncthreads();
    if (threadIdx.x == 0) *dtf = (cnt >= 1843) ? 1u : 0u;   // 90% of 2048
}

// ---------------------------------------------------------------- embedding
__global__ void embed_kernel(const int* __restrict__ words, const int* __restrict__ tags,
                             const void* __restrict__ wemb, const void* __restrict__ temb,
                             float* __restrict__ x /* [SEQ][400] f32 */,
                             const unsigned* __restrict__ dtf) {
    int t = blockIdx.x;
    int w = words[t], g = tags[t];
    int isbf = (int)*dtf;
    for (int k = threadIdx.x; k < HID; k += blockDim.x) {
        float v = (k < 300) ? loadx(wemb, (size_t)w * 300 + k, isbf)
                            : loadx(temb, (size_t)g * 100 + (k - 300), isbf);
        x[(size_t)t * HID + k] = v;
    }
}

// ---------------------------------------------------------- input projection
// xi[d][t][n] = sum_k A[t][k]*W[d*1600+n][k] + b_ih + b_hh
// 128x64 tile, 8x4 micro-acc per thread (FMA:LDS ratio 32:3).
__global__ __launch_bounds__(256) void proj_kernel(
        const float* __restrict__ A /* [SEQ][K] */,
        const void* __restrict__ Wraw /* [2][GATES][K] */,
        const void* __restrict__ bihRaw, const void* __restrict__ bhhRaw,
        float* __restrict__ xi /* [2][SEQ][GATES] */,
        int K, const unsigned* __restrict__ dtf) {
    const int isbf = (int)*dtf;
    __shared__ float As[16][132];
    __shared__ float Ws[16][68];
    int tid = threadIdx.x;
    int t0 = blockIdx.x * 128, n0 = blockIdx.y * 64, dir = blockIdx.z;
    int arow = tid >> 1, akoff = (tid & 1) * 8;
    int wrow = tid >> 2, wkoff = (tid & 3) * 4;
    int tx = (tid & 15) * 4;        // n-offset 0..63
    int ty = (tid >> 4) * 8;        // t-offset 0..127

    const float* Af = A + (size_t)(t0 + arow) * K + akoff;
    size_t wbase = (size_t)(dir * GATES + n0 + wrow) * K + wkoff;
    const float* Wf = (const float*)Wraw + wbase;
    const unsigned short* Wh = (const unsigned short*)Wraw + wbase;

    float acc[8][4] = {};
    for (int k0 = 0; k0 < K; k0 += 16) {
        float4 a0 = *(const float4*)(Af + k0);
        float4 a1 = *(const float4*)(Af + k0 + 4);
        float4 wv;
        if (isbf) {
            ushort4 w4 = *(const ushort4*)(Wh + k0);
            wv = make_float4(bf2f(w4.x), bf2f(w4.y), bf2f(w4.z), bf2f(w4.w));
        } else {
            wv = *(const float4*)(Wf + k0);
        }
        __syncthreads();
        As[akoff + 0][arow] = a0.x; As[akoff + 1][arow] = a0.y;
        As[akoff + 2][arow] = a0.z; As[akoff + 3][arow] = a0.w;
        As[akoff + 4][arow] = a1.x; As[akoff + 5][arow] = a1.y;
        As[akoff + 6][arow] = a1.z; As[akoff + 7][arow] = a1.w;
        Ws[wkoff + 0][wrow] = wv.x; Ws[wkoff + 1][wrow] = wv.y;
        Ws[wkoff + 2][wrow] = wv.z; Ws[wkoff + 3][wrow] = wv.w;
        __syncthreads();
#pragma unroll
        for (int kk = 0; kk < 16; ++kk) {
            float4 alo = *(const float4*)&As[kk][ty];
            float4 ahi = *(const float4*)&As[kk][ty + 4];
            float4 w4  = *(const float4*)&Ws[kk][tx];
            float av[8] = {alo.x, alo.y, alo.z, alo.w, ahi.x, ahi.y, ahi.z, ahi.w};
            float wvv[4] = {w4.x, w4.y, w4.z, w4.w};
#pragma unroll
            for (int i = 0; i < 8; ++i)
#pragma unroll
                for (int j = 0; j < 4; ++j)
                    acc[i][j] = fmaf(av[i], wvv[j], acc[i][j]);
        }
    }
    float bias[4];
#pragma unroll
    for (int j = 0; j < 4; ++j) {
        int n = n0 + tx + j;
        bias[j] = loadx(bihRaw, dir * GATES + n, isbf) + loadx(bhhRaw, dir * GATES + n, isbf);
    }
    float* xout = xi + (size_t)dir * SEQ * GATES;
#pragma unroll
    for (int i = 0; i < 8; ++i) {
        int t = t0 + ty + i;
        float4 o = make_float4(acc[i][0] + bias[0], acc[i][1] + bias[1],
                               acc[i][2] + bias[2], acc[i][3] + bias[3]);
        *(float4*)&xout[(size_t)t * GATES + n0 + tx] = o;
    }
}

// ------------------------------------------------------------- LSTM recurrence
// 20 WGs x 640 threads; WG owns 40 h-outputs (160 gate rows). Weights
// register-resident. Cross-WG h exchange through TAGGED 64-bit payloads:
// hx[t][e] = {tag = tagbase+step+1, f32 h}. Consumers poll the data words
// directly (no flags, no fences, no vmcnt drain on the critical path).
__global__ __launch_bounds__(640) void rec_kernel(
        const float* __restrict__ xi /* [2][SEQ][GATES] */,
        const void* __restrict__ whhRaw /* [2][GATES][HID] */,
        float* __restrict__ hout /* [SEQ][E1] plain, for downstream kernels */,
        unsigned long long* __restrict__ hx /* [SEQ][E1] tagged exchange */,
        unsigned tagbase,
        const unsigned* __restrict__ dtf) {
    int tid = threadIdx.x;
    int bid = blockIdx.x;          // 0..19
    int dir = bid / NWG;
    int wg  = bid % NWG;
    int chunk = tid % 20;
    int rg    = tid / 20;          // 0..31
    const int isbf = (int)*dtf;
    const int dirHID = dir * HID;

    __shared__ __align__(16) float hbuf[HID];
    __shared__ __align__(16) float partials[160][20];
    __shared__ __align__(16) float gates[160];

    // ---- load this lane's weight tile (stays in registers)
    float wv[5][20];
#pragma unroll
    for (int r = 0; r < 5; ++r) {
        int lr = rg * 5 + r;                // local row 0..159
        int jj = lr >> 2, gg = lr & 3;      // h index, gate (i,f,g,o)
        int grow = gg * HID + wg * 40 + jj; // global gate row
        size_t base = ((size_t)dir * GATES + grow) * HID + chunk * 20;
        if (isbf) {
            const ushort4* s4 = (const ushort4*)((const unsigned short*)whhRaw + base);
#pragma unroll
            for (int c4 = 0; c4 < 5; ++c4) {
                ushort4 w4 = s4[c4];
                wv[r][c4 * 4 + 0] = bf2f(w4.x); wv[r][c4 * 4 + 1] = bf2f(w4.y);
                wv[r][c4 * 4 + 2] = bf2f(w4.z); wv[r][c4 * 4 + 3] = bf2f(w4.w);
            }
        } else {
            const float4* s4 = (const float4*)((const float*)whhRaw + base);
#pragma unroll
            for (int c4 = 0; c4 < 5; ++c4) {
                float4 w4 = s4[c4];
                wv[r][c4 * 4 + 0] = w4.x; wv[r][c4 * 4 + 1] = w4.y;
                wv[r][c4 * 4 + 2] = w4.z; wv[r][c4 * 4 + 3] = w4.w;
            }
        }
    }

    int xrow = 0;
    if (tid < 160) { int jj = tid >> 2, gg = tid & 3; xrow = gg * HID + wg * 40 + jj; }
    const float* xibase = xi + (size_t)dir * SEQ * GATES;
    float cstate = 0.f;                    // lane tid<40 owns c for h-idx wg*40+tid
    size_t myelem = dirHID + wg * 40 + tid;  // publish slot (tid<40)

#pragma unroll 1
    for (int k = 0; k < SEQ; ++k) {
        int t = dir ? (SEQ - 1 - k) : k;
        float xiv = 0.f;
        if (tid < 160) xiv = xibase[(size_t)t * GATES + xrow];

        if (k > 0) {
            int tprev = dir ? (t + 1) : (t - 1);
            if (tid < HID) {
                const unsigned want = tagbase + (unsigned)k;
                const unsigned long long* p = &hx[(size_t)tprev * E1 + dirHID + tid];
                unsigned long long w;
                do {
                    w = __hip_atomic_load(p, __ATOMIC_RELAXED, __HIP_MEMORY_SCOPE_AGENT);
                } while ((unsigned)(w >> 32) != want);
                hbuf[tid] = __uint_as_float((unsigned)w);
            }
        } else {
            if (tid < HID) hbuf[tid] = 0.f;
        }
        __syncthreads();

        // ---- dot: 5 rows x 20 cols per lane, h broadcast from LDS
        float acc[5] = {0.f, 0.f, 0.f, 0.f, 0.f};
#pragma unroll
        for (int c4 = 0; c4 < 5; ++c4) {
            float4 hv = *(const float4*)&hbuf[chunk * 20 + c4 * 4];
#pragma unroll
            for (int r = 0; r < 5; ++r) {
                acc[r] += wv[r][c4 * 4 + 0] * hv.x + wv[r][c4 * 4 + 1] * hv.y +
                          wv[r][c4 * 4 + 2] * hv.z + wv[r][c4 * 4 + 3] * hv.w;
            }
        }
#pragma unroll
        for (int r = 0; r < 5; ++r) partials[rg * 5 + r][chunk] = acc[r];
        __syncthreads();

        // ---- reduce 20 column-chunks per gate row, add xi
        if (tid < 160) {
            const float4* pr = (const float4*)&partials[tid][0];
            float4 p0 = pr[0], p1 = pr[1], p2 = pr[2], p3 = pr[3], p4 = pr[4];
            float s = p0.x + p0.y + p0.z + p0.w
                    + p1.x + p1.y + p1.z + p1.w
                    + p2.x + p2.y + p2.z + p2.w
                    + p3.x + p3.y + p3.z + p3.w
                    + p4.x + p4.y + p4.z + p4.w;
            gates[tid] = s + xiv;
        }
        __syncthreads();

        // ---- nonlinearity + state update + tagged publish (no fence needed:
        //      tag and value share one atomic 64-bit word)
        if (tid < 40) {
            float4 g4 = *(const float4*)&gates[tid * 4];   // (i,f,g,o)
            float ig = sigm(g4.x), fg = sigm(g4.y), cg = tanh_f(g4.z), og = sigm(g4.w);
            cstate = fg * cstate + ig * cg;
            float hv = og * tanh_f(cstate);
            unsigned long long w =
                ((unsigned long long)(tagbase + (unsigned)k + 1u) << 32) |
                (unsigned long long)(unsigned)__float_as_uint(hv);
            __hip_atomic_store(&hx[(size_t)t * E1 + myelem], w,
                               __ATOMIC_RELAXED, __HIP_MEMORY_SCOPE_AGENT);
            hout[(size_t)t * E1 + myelem] = hv;   // plain copy for later kernels
        }
        // no barrier here: hbuf/partials/gates reuse is protected by the
        // barriers above in the next iteration
    }
}

// --------------------------------------------- head/dep projections (s, t)
__global__ void st_kernel(const float* __restrict__ h1 /* [SEQ][E1] */,
                          const void* __restrict__ fw /* [1600] */,
                          float* __restrict__ sv, float* __restrict__ tv,
                          const unsigned* __restrict__ dtf) {
    int i = blockIdx.x;
    int lane = threadIdx.x;
    int isbf = (int)*dtf;
    float s = 0.f, t = 0.f;
    for (int j = lane; j < E1; j += 64) {
        float hv = h1[(size_t)i * E1 + j];
        s += hv * loadx(fw, j, isbf);
        t += hv * loadx(fw, E1 + j, isbf);
    }
#pragma unroll
    for (int o = 32; o > 0; o >>= 1) {
        s += __shfl_xor(s, o, 64);
        t += __shfl_xor(t, o, 64);
    }
    if (lane == 0) { sv[i] = s; tv[i] = t; }
}

// ------------------------------------------------------------- final scores
__global__ void scores_kernel(const float* __restrict__ sv, const float* __restrict__ tv,
                              const void* __restrict__ fb, void* __restrict__ out,
                              const unsigned* __restrict__ dtf) {
    int idx = blockIdx.x * blockDim.x + threadIdx.x;   // < SEQ*SEQ
    int i = idx >> 9, j = idx & 511;
    int isbf = (int)*dtf;
    float v = tanh_f(sv[i] + tv[j] + loadx(fb, 0, isbf));
    if (isbf) ((unsigned short*)out)[idx] = f2bf(v);
    else      ((float*)out)[idx] = v;
}

// ---------------------------------------------------------------- workspace
static constexpr size_t OFF_X   = 0;           // 512*400*4   =   819,200
static constexpr size_t OFF_XI  = 819200;      // 2*512*1600*4 = 6,553,600
static constexpr size_t OFF_H0  = 7372800;     // 512*800*4   = 1,638,400
static constexpr size_t OFF_H1  = 9011200;     // 1,638,400
static constexpr size_t OFF_SV  = 10649600;    // 2048
static constexpr size_t OFF_TV  = 10651648;    // 2048
static constexpr size_t OFF_DTF = 10653696;    // 64
static constexpr size_t OFF_HX  = 10653760;    // 512*800*8 = 3,276,800 (tagged)

extern "C" void kernel_launch(void* const* d_in, const int* in_sizes, int n_in,
                              void* d_out, int out_size, void* d_ws, size_t ws_size,
                              hipStream_t stream) {
    const int* words = (const int*)d_in[0];
    const int* tags  = (const int*)d_in[1];
    const void* wemb = d_in[3];
    const void* temb = d_in[4];
    const void* wih0 = d_in[5];
    const void* whh0 = d_in[6];
    const void* bih0 = d_in[7];
    const void* bhh0 = d_in[8];
    const void* wih1 = d_in[9];
    const void* whh1 = d_in[10];
    const void* bih1 = d_in[11];
    const void* bhh1 = d_in[12];
    const void* fw   = d_in[13];
    const void* fb   = d_in[14];

    char* ws = (char*)d_ws;
    float* x                = (float*)(ws + OFF_X);
    float* xi               = (float*)(ws + OFF_XI);
    float* h0               = (float*)(ws + OFF_H0);
    float* h1               = (float*)(ws + OFF_H1);
    float* sv               = (float*)(ws + OFF_SV);
    float* tv               = (float*)(ws + OFF_TV);
    unsigned* dtf           = (unsigned*)(ws + OFF_DTF);
    unsigned long long* hx  = (unsigned long long*)(ws + OFF_HX);

    detect_kernel<<<1, 256, 0, stream>>>((const unsigned short*)wemb, dtf);
    embed_kernel<<<SEQ, 128, 0, stream>>>(words, tags, wemb, temb, x, dtf);

    // layer 0 (tags 1..512 in hx; 0xAAAAAAAA poison never matches)
    proj_kernel<<<dim3(4, 25, 2), 256, 0, stream>>>(x, wih0, bih0, bhh0, xi, HID, dtf);
    rec_kernel<<<2 * NWG, 640, 0, stream>>>(xi, whh0, h0, hx, 0u, dtf);

    // layer 1 (reuses xi and hx; tags 513..1024 disambiguate vs layer 0)
    proj_kernel<<<dim3(4, 25, 2), 256, 0, stream>>>(h0, wih1, bih1, bhh1, xi, E1, dtf);
    rec_kernel<<<2 * NWG, 640, 0, stream>>>(xi, whh1, h1, hx, 512u, dtf);

    // pairwise scores
    st_kernel<<<SEQ, 64, 0, stream>>>(h1, fw, sv, tv, dtf);
    scores_kernel<<<(SEQ * SEQ) / 256, 256, 0, stream>>>(sv, tv, fb, d_out, dtf);
}

// Round 4
// 2106.390 us; speedup vs baseline: 1.3282x; 1.0629x over previous
//
#include <hip/hip_runtime.h>

// Problem constants
#define SEQ 512
#define HID 400
#define GATES 1600   // 4*HID
#define E1 800       // 2*HID
#define TEAM 10      // workgroups per direction in the recurrence
#define RECGRID 160  // candidate WGs launched for team formation

__device__ __forceinline__ float bf2f(unsigned short u) {
    return __uint_as_float(((unsigned)u) << 16);
}
__device__ __forceinline__ unsigned short f2bf(float f) {
    unsigned u = __float_as_uint(f);
    u += 0x7FFFu + ((u >> 16) & 1u);   // RNE
    return (unsigned short)(u >> 16);
}
__device__ __forceinline__ float sigm(float x) { return 1.f / (1.f + __expf(-x)); }
__device__ __forceinline__ float tanh_f(float x) {
    float xc = fminf(fmaxf(x, -15.f), 15.f);
    float e = __expf(2.f * xc);
    return (e - 1.f) / (e + 1.f);
}
__device__ __forceinline__ float loadx(const void* p, size_t i, int isbf) {
    return isbf ? bf2f(((const unsigned short*)p)[i]) : ((const float*)p)[i];
}

// ------------------------------------------------------------ dtype detector
__global__ void detect_kernel(const unsigned short* __restrict__ wemb,
                              unsigned* __restrict__ dtf) {
    __shared__ int cnt;
    if (threadIdx.x == 0) cnt = 0;
    __syncthreads();
    int pass = 0;
    for (int i = 0; i < 8; ++i) {
        unsigned short u = wemb[threadIdx.x * 8 + i];
        int e = (u >> 7) & 0xFF;
        pass += (e >= 100 && e <= 130) ? 1 : 0;
    }
    atomicAdd(&cnt, pass);
    __syncthreads();
    if (threadIdx.x == 0) *dtf = (cnt >= 1843) ? 1u : 0u;   // 90% of 2048
}

// ---------------------------------------------------------------- embedding
__global__ void embed_kernel(const int* __restrict__ words, const int* __restrict__ tags,
                             const void* __restrict__ wemb, const void* __restrict__ temb,
                             float* __restrict__ x /* [SEQ][400] f32 */,
                             const unsigned* __restrict__ dtf) {
    int t = blockIdx.x;
    int w = words[t], g = tags[t];
    int isbf = (int)*dtf;
    for (int k = threadIdx.x; k < HID; k += blockDim.x) {
        float v = (k < 300) ? loadx(wemb, (size_t)w * 300 + k, isbf)
                            : loadx(temb, (size_t)g * 100 + (k - 300), isbf);
        x[(size_t)t * HID + k] = v;
    }
}

// ---------------------------------------------------------- input projection
// xi[d][t][n] = sum_k A[t][k]*W[d*1600+n][k] + b_ih + b_hh
// 128x64 tile, 8x4 micro-acc. A is either f32 [SEQ][K] (tagged=0) or tagged
// u64 [SEQ][K] with the f32 value in the low dword (tagged=1).
__global__ __launch_bounds__(256) void proj_kernel(
        const void* __restrict__ Araw, int tagged,
        const void* __restrict__ Wraw /* [2][GATES][K] */,
        const void* __restrict__ bihRaw, const void* __restrict__ bhhRaw,
        float* __restrict__ xi /* [2][SEQ][GATES] */,
        int K, const unsigned* __restrict__ dtf) {
    const int isbf = (int)*dtf;
    __shared__ float As[16][132];
    __shared__ float Ws[16][68];
    int tid = threadIdx.x;
    int t0 = blockIdx.x * 128, n0 = blockIdx.y * 64, dir = blockIdx.z;
    int arow = tid >> 1, akoff = (tid & 1) * 8;
    int wrow = tid >> 2, wkoff = (tid & 3) * 4;
    int tx = (tid & 15) * 4;        // n-offset 0..63
    int ty = (tid >> 4) * 8;        // t-offset 0..127

    const float* Af = (const float*)Araw + (size_t)(t0 + arow) * K + akoff;
    const unsigned long long* At = (const unsigned long long*)Araw +
                                   (size_t)(t0 + arow) * K + akoff;
    size_t wbase = (size_t)(dir * GATES + n0 + wrow) * K + wkoff;
    const float* Wf = (const float*)Wraw + wbase;
    const unsigned short* Wh = (const unsigned short*)Wraw + wbase;

    float acc[8][4] = {};
    for (int k0 = 0; k0 < K; k0 += 16) {
        float av8[8];
        if (tagged) {
            ulonglong2 q0 = *(const ulonglong2*)(At + k0);
            ulonglong2 q1 = *(const ulonglong2*)(At + k0 + 2);
            ulonglong2 q2 = *(const ulonglong2*)(At + k0 + 4);
            ulonglong2 q3 = *(const ulonglong2*)(At + k0 + 6);
            av8[0] = __uint_as_float((unsigned)q0.x); av8[1] = __uint_as_float((unsigned)q0.y);
            av8[2] = __uint_as_float((unsigned)q1.x); av8[3] = __uint_as_float((unsigned)q1.y);
            av8[4] = __uint_as_float((unsigned)q2.x); av8[5] = __uint_as_float((unsigned)q2.y);
            av8[6] = __uint_as_float((unsigned)q3.x); av8[7] = __uint_as_float((unsigned)q3.y);
        } else {
            float4 a0 = *(const float4*)(Af + k0);
            float4 a1 = *(const float4*)(Af + k0 + 4);
            av8[0] = a0.x; av8[1] = a0.y; av8[2] = a0.z; av8[3] = a0.w;
            av8[4] = a1.x; av8[5] = a1.y; av8[6] = a1.z; av8[7] = a1.w;
        }
        float4 wv;
        if (isbf) {
            ushort4 w4 = *(const ushort4*)(Wh + k0);
            wv = make_float4(bf2f(w4.x), bf2f(w4.y), bf2f(w4.z), bf2f(w4.w));
        } else {
            wv = *(const float4*)(Wf + k0);
        }
        __syncthreads();
#pragma unroll
        for (int i = 0; i < 8; ++i) As[akoff + i][arow] = av8[i];
        Ws[wkoff + 0][wrow] = wv.x; Ws[wkoff + 1][wrow] = wv.y;
        Ws[wkoff + 2][wrow] = wv.z; Ws[wkoff + 3][wrow] = wv.w;
        __syncthreads();
#pragma unroll
        for (int kk = 0; kk < 16; ++kk) {
            float4 alo = *(const float4*)&As[kk][ty];
            float4 ahi = *(const float4*)&As[kk][ty + 4];
            float4 w4  = *(const float4*)&Ws[kk][tx];
            float av[8] = {alo.x, alo.y, alo.z, alo.w, ahi.x, ahi.y, ahi.z, ahi.w};
            float wvv[4] = {w4.x, w4.y, w4.z, w4.w};
#pragma unroll
            for (int i = 0; i < 8; ++i)
#pragma unroll
                for (int j = 0; j < 4; ++j)
                    acc[i][j] = fmaf(av[i], wvv[j], acc[i][j]);
        }
    }
    float bias[4];
#pragma unroll
    for (int j = 0; j < 4; ++j) {
        int n = n0 + tx + j;
        bias[j] = loadx(bihRaw, dir * GATES + n, isbf) + loadx(bhhRaw, dir * GATES + n, isbf);
    }
    float* xout = xi + (size_t)dir * SEQ * GATES;
#pragma unroll
    for (int i = 0; i < 8; ++i) {
        int t = t0 + ty + i;
        float4 o = make_float4(acc[i][0] + bias[0], acc[i][1] + bias[1],
                               acc[i][2] + bias[2], acc[i][3] + bias[3]);
        *(float4*)&xout[(size_t)t * GATES + n0 + tx] = o;
    }
}

// ------------------------------------------------------------- LSTM recurrence
// Team formation: each WG reads its hardware XCC_ID, registers on a per-XCD
// counter; consecutive groups of TEAM co-located WGs form a team; first two
// complete teams claim fwd/bwd via CAS. Exchange = tagged 64-bit words via
// same-XCD L2 (volatile sc0 store/load, ~300cy RT) with a MALL backup channel
// (agent atomics) polled every 24 misses as hang insurance.
struct SyncArea { unsigned cnt[8]; unsigned claim[2]; unsigned pad[6]; };

__global__ __launch_bounds__(640) void rec_kernel(
        const float* __restrict__ xi /* [2][SEQ][GATES] */,
        const void* __restrict__ whhRaw /* [2][GATES][HID] */,
        unsigned long long* __restrict__ hx  /* [SEQ][E1] tagged, L2 path */,
        unsigned long long* __restrict__ hx2 /* [SEQ][E1] tagged, MALL backup */,
        unsigned tagbase, SyncArea* __restrict__ sy,
        const unsigned* __restrict__ dtf) {
    int tid = threadIdx.x;
    __shared__ int role[2];   // [0]=dir (0/1/2=exit), [1]=wg rank
    if (tid == 0) {
        unsigned xcd = __builtin_amdgcn_s_getreg((3 << 11) | 20) & 0xFu; // HW_REG_XCC_ID
        unsigned rank = atomicAdd(&sy->cnt[xcd], 1u);
        unsigned group = rank / TEAM;
        unsigned key = 1u + xcd * 64u + group;
        if ((rank % TEAM) == TEAM - 1) {          // group leader: claim a direction
            unsigned prev = atomicCAS(&sy->claim[0], 0u, key);
            if (prev != 0u) atomicCAS(&sy->claim[1], 0u, key);
        }
        int dir = -1;
        while (dir < 0) {
            unsigned c0 = __hip_atomic_load(&sy->claim[0], __ATOMIC_RELAXED,
                                            __HIP_MEMORY_SCOPE_AGENT);
            unsigned c1 = __hip_atomic_load(&sy->claim[1], __ATOMIC_RELAXED,
                                            __HIP_MEMORY_SCOPE_AGENT);
            if (c0 == key) dir = 0;
            else if (c1 == key) dir = 1;
            else if (c0 != 0u && c1 != 0u) dir = 2;
        }
        role[0] = dir;
        role[1] = (int)(rank % TEAM);
    }
    __syncthreads();
    const int dir = role[0];
    const int wg  = role[1];
    if (dir == 2) return;                          // not a claimed team

    int chunk = tid % 20;
    int rg    = tid / 20;          // 0..31
    const int isbf = (int)*dtf;
    const int dirHID = dir * HID;

    __shared__ __align__(16) float hbuf[HID];
    __shared__ __align__(16) float partials[160][20];
    __shared__ __align__(16) float gates[160];

    // ---- load this lane's weight tile (stays in registers)
    float wv[5][20];
#pragma unroll
    for (int r = 0; r < 5; ++r) {
        int lr = rg * 5 + r;                // local row 0..159
        int jj = lr >> 2, gg = lr & 3;      // h index, gate (i,f,g,o)
        int grow = gg * HID + wg * 40 + jj; // global gate row
        size_t base = ((size_t)dir * GATES + grow) * HID + chunk * 20;
        if (isbf) {
            const ushort4* s4 = (const ushort4*)((const unsigned short*)whhRaw + base);
#pragma unroll
            for (int c4 = 0; c4 < 5; ++c4) {
                ushort4 w4 = s4[c4];
                wv[r][c4 * 4 + 0] = bf2f(w4.x); wv[r][c4 * 4 + 1] = bf2f(w4.y);
                wv[r][c4 * 4 + 2] = bf2f(w4.z); wv[r][c4 * 4 + 3] = bf2f(w4.w);
            }
        } else {
            const float4* s4 = (const float4*)((const float*)whhRaw + base);
#pragma unroll
            for (int c4 = 0; c4 < 5; ++c4) {
                float4 w4 = s4[c4];
                wv[r][c4 * 4 + 0] = w4.x; wv[r][c4 * 4 + 1] = w4.y;
                wv[r][c4 * 4 + 2] = w4.z; wv[r][c4 * 4 + 3] = w4.w;
            }
        }
    }

    int xrow = 0;
    if (tid < 160) { int jj = tid >> 2, gg = tid & 3; xrow = gg * HID + wg * 40 + jj; }
    const float* xibase = xi + (size_t)dir * SEQ * GATES;
    float cstate = 0.f;                      // lane tid<40 owns c for h-idx wg*40+tid
    size_t myelem = dirHID + wg * 40 + tid;  // publish slot (tid<40)

#pragma unroll 1
    for (int k = 0; k < SEQ; ++k) {
        int t = dir ? (SEQ - 1 - k) : k;
        float xiv = 0.f;
        if (tid < 160) xiv = xibase[(size_t)t * GATES + xrow];

        if (k > 0) {
            int tprev = dir ? (t + 1) : (t - 1);
            if (tid < HID) {
                const unsigned want = tagbase + (unsigned)k;
                size_t eidx = (size_t)tprev * E1 + dirHID + tid;
                const volatile unsigned long long* p =
                    (const volatile unsigned long long*)&hx[eidx];
                unsigned long long w;
                int spin = 0;
                for (;;) {
                    w = *p;                               // sc0: same-XCD L2
                    if ((unsigned)(w >> 32) == want) break;
                    if (++spin >= 24) {                   // MALL fallback (insurance)
                        w = __hip_atomic_load(&hx2[eidx], __ATOMIC_RELAXED,
                                              __HIP_MEMORY_SCOPE_AGENT);
                        if ((unsigned)(w >> 32) == want) break;
                        spin = 0;
                    }
                }
                hbuf[tid] = __uint_as_float((unsigned)w);
            }
        } else {
            if (tid < HID) hbuf[tid] = 0.f;
        }
        __syncthreads();

        // ---- dot: 5 rows x 20 cols per lane, h broadcast from LDS
        float acc[5] = {0.f, 0.f, 0.f, 0.f, 0.f};
#pragma unroll
        for (int c4 = 0; c4 < 5; ++c4) {
            float4 hv = *(const float4*)&hbuf[chunk * 20 + c4 * 4];
#pragma unroll
            for (int r = 0; r < 5; ++r) {
                acc[r] += wv[r][c4 * 4 + 0] * hv.x + wv[r][c4 * 4 + 1] * hv.y +
                          wv[r][c4 * 4 + 2] * hv.z + wv[r][c4 * 4 + 3] * hv.w;
            }
        }
#pragma unroll
        for (int r = 0; r < 5; ++r) partials[rg * 5 + r][chunk] = acc[r];
        __syncthreads();

        // ---- reduce 20 column-chunks per gate row, add xi
        if (tid < 160) {
            const float4* pr = (const float4*)&partials[tid][0];
            float4 p0 = pr[0], p1 = pr[1], p2 = pr[2], p3 = pr[3], p4 = pr[4];
            float s = p0.x + p0.y + p0.z + p0.w
                    + p1.x + p1.y + p1.z + p1.w
                    + p2.x + p2.y + p2.z + p2.w
                    + p3.x + p3.y + p3.z + p3.w
                    + p4.x + p4.y + p4.z + p4.w;
            gates[tid] = s + xiv;
        }
        __syncthreads();

        // ---- nonlinearity + state update + tagged publish
        if (tid < 40) {
            float4 g4 = *(const float4*)&gates[tid * 4];   // (i,f,g,o)
            float ig = sigm(g4.x), fg = sigm(g4.y), cg = tanh_f(g4.z), og = sigm(g4.w);
            cstate = fg * cstate + ig * cg;
            float hv = og * tanh_f(cstate);
            unsigned long long w =
                ((unsigned long long)(tagbase + (unsigned)k + 1u) << 32) |
                (unsigned long long)(unsigned)__float_as_uint(hv);
            size_t eidx = (size_t)t * E1 + myelem;
            *(volatile unsigned long long*)&hx[eidx] = w;          // L2 fast path
            __hip_atomic_store(&hx2[eidx], w, __ATOMIC_RELAXED,
                               __HIP_MEMORY_SCOPE_AGENT);          // MALL backup
        }
        // no trailing barrier: next iteration's barriers protect LDS reuse
    }
}

// --------------------------------------------- head/dep projections (s, t)
__global__ void st_kernel(const unsigned long long* __restrict__ h1x /* tagged */,
                          const void* __restrict__ fw /* [1600] */,
                          float* __restrict__ sv, float* __restrict__ tv,
                          const unsigned* __restrict__ dtf) {
    int i = blockIdx.x;
    int lane = threadIdx.x;
    int isbf = (int)*dtf;
    float s = 0.f, t = 0.f;
    for (int j = lane; j < E1; j += 64) {
        float hv = __uint_as_float((unsigned)h1x[(size_t)i * E1 + j]);
        s += hv * loadx(fw, j, isbf);
        t += hv * loadx(fw, E1 + j, isbf);
    }
#pragma unroll
    for (int o = 32; o > 0; o >>= 1) {
        s += __shfl_xor(s, o, 64);
        t += __shfl_xor(t, o, 64);
    }
    if (lane == 0) { sv[i] = s; tv[i] = t; }
}

// ------------------------------------------------------------- final scores
__global__ void scores_kernel(const float* __restrict__ sv, const float* __restrict__ tv,
                              const void* __restrict__ fb, void* __restrict__ out,
                              const unsigned* __restrict__ dtf) {
    int idx = blockIdx.x * blockDim.x + threadIdx.x;   // < SEQ*SEQ
    int i = idx >> 9, j = idx & 511;
    int isbf = (int)*dtf;
    float v = tanh_f(sv[i] + tv[j] + loadx(fb, 0, isbf));
    if (isbf) ((unsigned short*)out)[idx] = f2bf(v);
    else      ((float*)out)[idx] = v;
}

// ---------------------------------------------------------------- workspace
static constexpr size_t OFF_X    = 0;          // 512*400*4    =   819,200
static constexpr size_t OFF_XI   = 819200;     // 2*512*1600*4 = 6,553,600
static constexpr size_t OFF_SV   = 7372800;    // 2048
static constexpr size_t OFF_TV   = 7374848;    // 2048
static constexpr size_t OFF_DTF  = 7376896;    // 64
static constexpr size_t OFF_SYNC = 7376960;    // 2 * 64 (formation areas)
static constexpr size_t OFF_HX   = 7377216;    // 512*800*8 = 3,276,800
static constexpr size_t OFF_HX2  = 10654016;   // 512*800*8 = 3,276,800 (ends 13.93 MB)

extern "C" void kernel_launch(void* const* d_in, const int* in_sizes, int n_in,
                              void* d_out, int out_size, void* d_ws, size_t ws_size,
                              hipStream_t stream) {
    const int* words = (const int*)d_in[0];
    const int* tags  = (const int*)d_in[1];
    const void* wemb = d_in[3];
    const void* temb = d_in[4];
    const void* wih0 = d_in[5];
    const void* whh0 = d_in[6];
    const void* bih0 = d_in[7];
    const void* bhh0 = d_in[8];
    const void* wih1 = d_in[9];
    const void* whh1 = d_in[10];
    const void* bih1 = d_in[11];
    const void* bhh1 = d_in[12];
    const void* fw   = d_in[13];
    const void* fb   = d_in[14];

    char* ws = (char*)d_ws;
    float* x               = (float*)(ws + OFF_X);
    float* xi              = (float*)(ws + OFF_XI);
    float* sv              = (float*)(ws + OFF_SV);
    float* tv              = (float*)(ws + OFF_TV);
    unsigned* dtf          = (unsigned*)(ws + OFF_DTF);
    SyncArea* sync0        = (SyncArea*)(ws + OFF_SYNC);
    SyncArea* sync1        = (SyncArea*)(ws + OFF_SYNC + 64);
    unsigned long long* hx  = (unsigned long long*)(ws + OFF_HX);
    unsigned long long* hx2 = (unsigned long long*)(ws + OFF_HX2);

    // formation counters/claims must start at 0 (ws re-poisoned to 0xAA)
    hipMemsetAsync(ws + OFF_SYNC, 0, 128, stream);
    detect_kernel<<<1, 256, 0, stream>>>((const unsigned short*)wemb, dtf);
    embed_kernel<<<SEQ, 128, 0, stream>>>(words, tags, wemb, temb, x, dtf);

    // layer 0 (tags 1..512; 0xAAAAAAAA poison never matches)
    proj_kernel<<<dim3(4, 25, 2), 256, 0, stream>>>(x, 0, wih0, bih0, bhh0, xi, HID, dtf);
    rec_kernel<<<RECGRID, 640, 0, stream>>>(xi, whh0, hx, hx2, 0u, sync0, dtf);

    // layer 1 (reuses xi and hx; tags 513..1024 disambiguate vs layer 0)
    proj_kernel<<<dim3(4, 25, 2), 256, 0, stream>>>(hx, 1, wih1, bih1, bhh1, xi, E1, dtf);
    rec_kernel<<<RECGRID, 640, 0, stream>>>(xi, whh1, hx, hx2, 512u, sync1, dtf);

    // pairwise scores
    st_kernel<<<SEQ, 64, 0, stream>>>(hx, fw, sv, tv, dtf);
    scores_kernel<<<(SEQ * SEQ) / 256, 256, 0, stream>>>(sv, tv, fb, d_out, dtf);
}

// Round 5
// 1968.436 us; speedup vs baseline: 1.4213x; 1.0701x over previous
//
#include <hip/hip_runtime.h>

// Problem constants
#define SEQ 512
#define HID 400
#define GATES 1600   // 4*HID
#define E1 800       // 2*HID
#define TEAM 10      // workgroups per direction in the recurrence
#define RECGRID 160  // candidate WGs launched for team formation

__device__ __forceinline__ float bf2f(unsigned short u) {
    return __uint_as_float(((unsigned)u) << 16);
}
__device__ __forceinline__ unsigned short f2bf(float f) {
    unsigned u = __float_as_uint(f);
    u += 0x7FFFu + ((u >> 16) & 1u);   // RNE
    return (unsigned short)(u >> 16);
}
__device__ __forceinline__ float sigm(float x) { return 1.f / (1.f + __expf(-x)); }
__device__ __forceinline__ float tanh_f(float x) {
    float xc = fminf(fmaxf(x, -15.f), 15.f);
    float e = __expf(2.f * xc);
    return (e - 1.f) / (e + 1.f);
}
__device__ __forceinline__ float loadx(const void* p, size_t i, int isbf) {
    return isbf ? bf2f(((const unsigned short*)p)[i]) : ((const float*)p)[i];
}

// ------------------------------------------------------------ dtype detector
__global__ void detect_kernel(const unsigned short* __restrict__ wemb,
                              unsigned* __restrict__ dtf) {
    __shared__ int cnt;
    if (threadIdx.x == 0) cnt = 0;
    __syncthreads();
    int pass = 0;
    for (int i = 0; i < 8; ++i) {
        unsigned short u = wemb[threadIdx.x * 8 + i];
        int e = (u >> 7) & 0xFF;
        pass += (e >= 100 && e <= 130) ? 1 : 0;
    }
    atomicAdd(&cnt, pass);
    __syncthreads();
    if (threadIdx.x == 0) *dtf = (cnt >= 1843) ? 1u : 0u;   // 90% of 2048
}

// ---------------------------------------------------------------- embedding
__global__ void embed_kernel(const int* __restrict__ words, const int* __restrict__ tags,
                             const void* __restrict__ wemb, const void* __restrict__ temb,
                             float* __restrict__ x /* [SEQ][400] f32 */,
                             const unsigned* __restrict__ dtf) {
    int t = blockIdx.x;
    int w = words[t], g = tags[t];
    int isbf = (int)*dtf;
    for (int k = threadIdx.x; k < HID; k += blockDim.x) {
        float v = (k < 300) ? loadx(wemb, (size_t)w * 300 + k, isbf)
                            : loadx(temb, (size_t)g * 100 + (k - 300), isbf);
        x[(size_t)t * HID + k] = v;
    }
}

// ---------------------------------------------------------- input projection
// xi[d][t][n] = sum_k A[t][k]*W[d*1600+n][k] + b_ih + b_hh
// 128x64 tile, 8x4 micro-acc. A is either f32 [SEQ][K] (tagged=0) or tagged
// u64 [SEQ][K] with the f32 value in the low dword (tagged=1).
__global__ __launch_bounds__(256) void proj_kernel(
        const void* __restrict__ Araw, int tagged,
        const void* __restrict__ Wraw /* [2][GATES][K] */,
        const void* __restrict__ bihRaw, const void* __restrict__ bhhRaw,
        float* __restrict__ xi /* [2][SEQ][GATES] */,
        int K, const unsigned* __restrict__ dtf) {
    const int isbf = (int)*dtf;
    __shared__ float As[16][132];
    __shared__ float Ws[16][68];
    int tid = threadIdx.x;
    int t0 = blockIdx.x * 128, n0 = blockIdx.y * 64, dir = blockIdx.z;
    int arow = tid >> 1, akoff = (tid & 1) * 8;
    int wrow = tid >> 2, wkoff = (tid & 3) * 4;
    int tx = (tid & 15) * 4;        // n-offset 0..63
    int ty = (tid >> 4) * 8;        // t-offset 0..127

    const float* Af = (const float*)Araw + (size_t)(t0 + arow) * K + akoff;
    const unsigned long long* At = (const unsigned long long*)Araw +
                                   (size_t)(t0 + arow) * K + akoff;
    size_t wbase = (size_t)(dir * GATES + n0 + wrow) * K + wkoff;
    const float* Wf = (const float*)Wraw + wbase;
    const unsigned short* Wh = (const unsigned short*)Wraw + wbase;

    float acc[8][4] = {};
    for (int k0 = 0; k0 < K; k0 += 16) {
        float av8[8];
        if (tagged) {
            ulonglong2 q0 = *(const ulonglong2*)(At + k0);
            ulonglong2 q1 = *(const ulonglong2*)(At + k0 + 2);
            ulonglong2 q2 = *(const ulonglong2*)(At + k0 + 4);
            ulonglong2 q3 = *(const ulonglong2*)(At + k0 + 6);
            av8[0] = __uint_as_float((unsigned)q0.x); av8[1] = __uint_as_float((unsigned)q0.y);
            av8[2] = __uint_as_float((unsigned)q1.x); av8[3] = __uint_as_float((unsigned)q1.y);
            av8[4] = __uint_as_float((unsigned)q2.x); av8[5] = __uint_as_float((unsigned)q2.y);
            av8[6] = __uint_as_float((unsigned)q3.x); av8[7] = __uint_as_float((unsigned)q3.y);
        } else {
            float4 a0 = *(const float4*)(Af + k0);
            float4 a1 = *(const float4*)(Af + k0 + 4);
            av8[0] = a0.x; av8[1] = a0.y; av8[2] = a0.z; av8[3] = a0.w;
            av8[4] = a1.x; av8[5] = a1.y; av8[6] = a1.z; av8[7] = a1.w;
        }
        float4 wv;
        if (isbf) {
            ushort4 w4 = *(const ushort4*)(Wh + k0);
            wv = make_float4(bf2f(w4.x), bf2f(w4.y), bf2f(w4.z), bf2f(w4.w));
        } else {
            wv = *(const float4*)(Wf + k0);
        }
        __syncthreads();
#pragma unroll
        for (int i = 0; i < 8; ++i) As[akoff + i][arow] = av8[i];
        Ws[wkoff + 0][wrow] = wv.x; Ws[wkoff + 1][wrow] = wv.y;
        Ws[wkoff + 2][wrow] = wv.z; Ws[wkoff + 3][wrow] = wv.w;
        __syncthreads();
#pragma unroll
        for (int kk = 0; kk < 16; ++kk) {
            float4 alo = *(const float4*)&As[kk][ty];
            float4 ahi = *(const float4*)&As[kk][ty + 4];
            float4 w4  = *(const float4*)&Ws[kk][tx];
            float av[8] = {alo.x, alo.y, alo.z, alo.w, ahi.x, ahi.y, ahi.z, ahi.w};
            float wvv[4] = {w4.x, w4.y, w4.z, w4.w};
#pragma unroll
            for (int i = 0; i < 8; ++i)
#pragma unroll
                for (int j = 0; j < 4; ++j)
                    acc[i][j] = fmaf(av[i], wvv[j], acc[i][j]);
        }
    }
    float bias[4];
#pragma unroll
    for (int j = 0; j < 4; ++j) {
        int n = n0 + tx + j;
        bias[j] = loadx(bihRaw, dir * GATES + n, isbf) + loadx(bhhRaw, dir * GATES + n, isbf);
    }
    float* xout = xi + (size_t)dir * SEQ * GATES;
#pragma unroll
    for (int i = 0; i < 8; ++i) {
        int t = t0 + ty + i;
        float4 o = make_float4(acc[i][0] + bias[0], acc[i][1] + bias[1],
                               acc[i][2] + bias[2], acc[i][3] + bias[3]);
        *(float4*)&xout[(size_t)t * GATES + n0 + tx] = o;
    }
}

// ------------------------------------------------------------- LSTM recurrence
// 512 threads/WG (8 waves = 2/SIMD exactly), __launch_bounds__(512,2) gives a
// 256-VGPR budget so the 125-f32 weight tile STAYS IN REGISTERS (round-4 ran
// at VGPR_Count=72 -> the wv tile was spilled to scratch and re-read every
// step; that was the hidden 2000+ cy/step).
// Mapping: rg=tid>>4 (0..31) owns rows rg*5..+4; chunk=tid&15 owns cols
// chunk*25..+24. Cross-WG exchange: tagged u64 via same-XCD L2 (team
// formation by hardware XCC_ID), MALL backup channel as hang insurance.
struct SyncArea { unsigned cnt[8]; unsigned claim[2]; unsigned pad[6]; };

__global__ __launch_bounds__(512, 2) void rec_kernel(
        const float* __restrict__ xi /* [2][SEQ][GATES] */,
        const void* __restrict__ whhRaw /* [2][GATES][HID] */,
        unsigned long long* __restrict__ hx  /* [SEQ][E1] tagged, L2 path */,
        unsigned long long* __restrict__ hx2 /* [SEQ][E1] tagged, MALL backup */,
        unsigned tagbase, SyncArea* __restrict__ sy,
        const unsigned* __restrict__ dtf) {
    int tid = threadIdx.x;
    __shared__ int role[2];   // [0]=dir (0/1/2=exit), [1]=wg rank
    if (tid == 0) {
        unsigned xcd = __builtin_amdgcn_s_getreg((3 << 11) | 20) & 0xFu; // HW_REG_XCC_ID
        unsigned rank = atomicAdd(&sy->cnt[xcd], 1u);
        unsigned group = rank / TEAM;
        unsigned key = 1u + xcd * 64u + group;
        if ((rank % TEAM) == TEAM - 1) {          // group leader: claim a direction
            unsigned prev = atomicCAS(&sy->claim[0], 0u, key);
            if (prev != 0u) atomicCAS(&sy->claim[1], 0u, key);
        }
        int dir = -1;
        while (dir < 0) {
            unsigned c0 = __hip_atomic_load(&sy->claim[0], __ATOMIC_RELAXED,
                                            __HIP_MEMORY_SCOPE_AGENT);
            unsigned c1 = __hip_atomic_load(&sy->claim[1], __ATOMIC_RELAXED,
                                            __HIP_MEMORY_SCOPE_AGENT);
            if (c0 == key) dir = 0;
            else if (c1 == key) dir = 1;
            else if (c0 != 0u && c1 != 0u) dir = 2;
        }
        role[0] = dir;
        role[1] = (int)(rank % TEAM);
    }
    __syncthreads();
    const int dir = role[0];
    const int wg  = role[1];
    if (dir == 2) return;                          // not a claimed team

    int chunk = tid & 15;          // 0..15 -> cols chunk*25..+24
    int rg    = tid >> 4;          // 0..31 -> rows rg*5..+4
    const int isbf = (int)*dtf;
    const int dirHID = dir * HID;

    __shared__ __align__(16) float hbuf[HID];
    __shared__ __align__(16) float partials[160][20];  // 16 cols used, 20 for bank/align
    __shared__ __align__(16) float gates[160];

    // ---- load this lane's weight tile: 5 rows x 25 cols, REGISTER-resident
    float wv[5][25];
#pragma unroll
    for (int r = 0; r < 5; ++r) {
        int lr = rg * 5 + r;                // local row 0..159
        int jj = lr >> 2, gg = lr & 3;      // h index, gate (i,f,g,o)
        int grow = gg * HID + wg * 40 + jj; // global gate row
        size_t base = ((size_t)dir * GATES + grow) * HID + chunk * 25;
        if (isbf) {
            const unsigned short* p = (const unsigned short*)whhRaw + base;
#pragma unroll
            for (int c = 0; c < 25; ++c) wv[r][c] = bf2f(p[c]);
        } else {
            const float* p = (const float*)whhRaw + base;
#pragma unroll
            for (int c = 0; c < 25; ++c) wv[r][c] = p[c];
        }
    }

    int xrow = 0;
    if (tid < 160) { int jj = tid >> 2, gg = tid & 3; xrow = gg * HID + wg * 40 + jj; }
    const float* xibase = xi + (size_t)dir * SEQ * GATES;
    float cstate = 0.f;                      // lane tid<40 owns c for h-idx wg*40+tid
    size_t myelem = dirHID + wg * 40 + tid;  // publish slot (tid<40)

#pragma unroll 1
    for (int k = 0; k < SEQ; ++k) {
        int t = dir ? (SEQ - 1 - k) : k;
        float xiv = 0.f;
        if (tid < 160) xiv = xibase[(size_t)t * GATES + xrow];

        if (k > 0) {
            int tprev = dir ? (t + 1) : (t - 1);
            if (tid < HID) {
                const unsigned want = tagbase + (unsigned)k;
                size_t eidx = (size_t)tprev * E1 + dirHID + tid;
                const volatile unsigned long long* p =
                    (const volatile unsigned long long*)&hx[eidx];
                unsigned long long w;
                int spin = 0;
                for (;;) {
                    w = *p;                               // sc0: same-XCD L2
                    if ((unsigned)(w >> 32) == want) break;
                    if (++spin >= 24) {                   // MALL fallback (insurance)
                        w = __hip_atomic_load(&hx2[eidx], __ATOMIC_RELAXED,
                                              __HIP_MEMORY_SCOPE_AGENT);
                        if ((unsigned)(w >> 32) == want) break;
                        spin = 0;
                    }
                }
                hbuf[tid] = __uint_as_float((unsigned)w);
            }
        } else {
            if (tid < HID) hbuf[tid] = 0.f;
        }
        __syncthreads();

        // ---- dot: 5 rows x 25 cols per lane; h broadcast from LDS
        //      (16 distinct banks across chunks -> conflict-free broadcast)
        float acc[5] = {0.f, 0.f, 0.f, 0.f, 0.f};
#pragma unroll
        for (int c = 0; c < 25; ++c) {
            float hv = hbuf[chunk * 25 + c];
#pragma unroll
            for (int r = 0; r < 5; ++r)
                acc[r] = fmaf(wv[r][c], hv, acc[r]);
        }
#pragma unroll
        for (int r = 0; r < 5; ++r) partials[rg * 5 + r][chunk] = acc[r];
        __syncthreads();

        // ---- reduce 16 column-chunks per gate row, add xi
        if (tid < 160) {
            const float4* pr = (const float4*)&partials[tid][0];
            float4 p0 = pr[0], p1 = pr[1], p2 = pr[2], p3 = pr[3];
            float s = p0.x + p0.y + p0.z + p0.w
                    + p1.x + p1.y + p1.z + p1.w
                    + p2.x + p2.y + p2.z + p2.w
                    + p3.x + p3.y + p3.z + p3.w;
            gates[tid] = s + xiv;
        }
        __syncthreads();

        // ---- nonlinearity + state update + tagged publish
        if (tid < 40) {
            float4 g4 = *(const float4*)&gates[tid * 4];   // (i,f,g,o)
            float ig = sigm(g4.x), fg = sigm(g4.y), cg = tanh_f(g4.z), og = sigm(g4.w);
            cstate = fg * cstate + ig * cg;
            float hv = og * tanh_f(cstate);
            unsigned long long w =
                ((unsigned long long)(tagbase + (unsigned)k + 1u) << 32) |
                (unsigned long long)(unsigned)__float_as_uint(hv);
            size_t eidx = (size_t)t * E1 + myelem;
            *(volatile unsigned long long*)&hx[eidx] = w;          // L2 fast path
            __hip_atomic_store(&hx2[eidx], w, __ATOMIC_RELAXED,
                               __HIP_MEMORY_SCOPE_AGENT);          // MALL backup
        }
        // no trailing barrier: next iteration's barriers protect LDS reuse
    }
}

// --------------------------------------------- head/dep projections (s, t)
__global__ void st_kernel(const unsigned long long* __restrict__ h1x /* tagged */,
                          const void* __restrict__ fw /* [1600] */,
                          float* __restrict__ sv, float* __restrict__ tv,
                          const unsigned* __restrict__ dtf) {
    int i = blockIdx.x;
    int lane = threadIdx.x;
    int isbf = (int)*dtf;
    float s = 0.f, t = 0.f;
    for (int j = lane; j < E1; j += 64) {
        float hv = __uint_as_float((unsigned)h1x[(size_t)i * E1 + j]);
        s += hv * loadx(fw, j, isbf);
        t += hv * loadx(fw, E1 + j, isbf);
    }
#pragma unroll
    for (int o = 32; o > 0; o >>= 1) {
        s += __shfl_xor(s, o, 64);
        t += __shfl_xor(t, o, 64);
    }
    if (lane == 0) { sv[i] = s; tv[i] = t; }
}

// ------------------------------------------------------------- final scores
__global__ void scores_kernel(const float* __restrict__ sv, const float* __restrict__ tv,
                              const void* __restrict__ fb, void* __restrict__ out,
                              const unsigned* __restrict__ dtf) {
    int idx = blockIdx.x * blockDim.x + threadIdx.x;   // < SEQ*SEQ
    int i = idx >> 9, j = idx & 511;
    int isbf = (int)*dtf;
    float v = tanh_f(sv[i] + tv[j] + loadx(fb, 0, isbf));
    if (isbf) ((unsigned short*)out)[idx] = f2bf(v);
    else      ((float*)out)[idx] = v;
}

// ---------------------------------------------------------------- workspace
static constexpr size_t OFF_X    = 0;          // 512*400*4    =   819,200
static constexpr size_t OFF_XI   = 819200;     // 2*512*1600*4 = 6,553,600
static constexpr size_t OFF_SV   = 7372800;    // 2048
static constexpr size_t OFF_TV   = 7374848;    // 2048
static constexpr size_t OFF_DTF  = 7376896;    // 64
static constexpr size_t OFF_SYNC = 7376960;    // 2 * 64 (formation areas)
static constexpr size_t OFF_HX   = 7377216;    // 512*800*8 = 3,276,800
static constexpr size_t OFF_HX2  = 10654016;   // 512*800*8 = 3,276,800 (ends 13.93 MB)

extern "C" void kernel_launch(void* const* d_in, const int* in_sizes, int n_in,
                              void* d_out, int out_size, void* d_ws, size_t ws_size,
                              hipStream_t stream) {
    const int* words = (const int*)d_in[0];
    const int* tags  = (const int*)d_in[1];
    const void* wemb = d_in[3];
    const void* temb = d_in[4];
    const void* wih0 = d_in[5];
    const void* whh0 = d_in[6];
    const void* bih0 = d_in[7];
    const void* bhh0 = d_in[8];
    const void* wih1 = d_in[9];
    const void* whh1 = d_in[10];
    const void* bih1 = d_in[11];
    const void* bhh1 = d_in[12];
    const void* fw   = d_in[13];
    const void* fb   = d_in[14];

    char* ws = (char*)d_ws;
    float* x               = (float*)(ws + OFF_X);
    float* xi              = (float*)(ws + OFF_XI);
    float* sv              = (float*)(ws + OFF_SV);
    float* tv              = (float*)(ws + OFF_TV);
    unsigned* dtf          = (unsigned*)(ws + OFF_DTF);
    SyncArea* sync0        = (SyncArea*)(ws + OFF_SYNC);
    SyncArea* sync1        = (SyncArea*)(ws + OFF_SYNC + 64);
    unsigned long long* hx  = (unsigned long long*)(ws + OFF_HX);
    unsigned long long* hx2 = (unsigned long long*)(ws + OFF_HX2);

    // formation counters/claims must start at 0 (ws re-poisoned to 0xAA)
    hipMemsetAsync(ws + OFF_SYNC, 0, 128, stream);
    detect_kernel<<<1, 256, 0, stream>>>((const unsigned short*)wemb, dtf);
    embed_kernel<<<SEQ, 128, 0, stream>>>(words, tags, wemb, temb, x, dtf);

    // layer 0 (tags 1..512; 0xAAAAAAAA poison never matches)
    proj_kernel<<<dim3(4, 25, 2), 256, 0, stream>>>(x, 0, wih0, bih0, bhh0, xi, HID, dtf);
    rec_kernel<<<RECGRID, 512, 0, stream>>>(xi, whh0, hx, hx2, 0u, sync0, dtf);

    // layer 1 (reuses xi and hx; tags 513..1024 disambiguate vs layer 0)
    proj_kernel<<<dim3(4, 25, 2), 256, 0, stream>>>(hx, 1, wih1, bih1, bhh1, xi, E1, dtf);
    rec_kernel<<<RECGRID, 512, 0, stream>>>(xi, whh1, hx, hx2, 512u, sync1, dtf);

    // pairwise scores
    st_kernel<<<SEQ, 64, 0, stream>>>(hx, fw, sv, tv, dtf);
    scores_kernel<<<(SEQ * SEQ) / 256, 256, 0, stream>>>(sv, tv, fb, d_out, dtf);
}